// Round 19
// baseline (274.100 us; speedup 1.0000x reference)
//
#include <hip/hip_runtime.h>
#include <hip/hip_bf16.h>

// Child-Sum Tree-LSTM, 16 trees x branch4 x depth8, HIDDEN=IN_DIM=128.
// R19 = R16 + (a) leaf/internal: parent-x A-frags loaded directly from global
//       (sxp LDS staging removed; bit-identical math), and (b) levels 2..0 +
//       output head fused into ONE 4-block kernel (block = 4 trees; same-block
//       global RAW via __syncthreads -- no cross-block coherence needed).

#define HID 128

typedef unsigned short u16;
typedef unsigned int u32;
typedef __attribute__((ext_vector_type(8))) short short8;
typedef __attribute__((ext_vector_type(4))) float floatx4;

__device__ __forceinline__ float bf2f(u16 u) {
  union { unsigned int u; float f; } v; v.u = ((unsigned int)u) << 16; return v.f;
}
__device__ __forceinline__ u16 f2bf(float f) {
  __hip_bfloat16 b = __float2bfloat16(f);           // native RNE cvt on gfx950
  return *reinterpret_cast<u16*>(&b);
}
__device__ __forceinline__ short8 f2bf8(float4 f0, float4 f1) {
  short8 s;
  s[0] = (short)f2bf(f0.x); s[1] = (short)f2bf(f0.y);
  s[2] = (short)f2bf(f0.z); s[3] = (short)f2bf(f0.w);
  s[4] = (short)f2bf(f1.x); s[5] = (short)f2bf(f1.y);
  s[6] = (short)f2bf(f1.z); s[7] = (short)f2bf(f1.w);
  return s;
}
__device__ __forceinline__ float sigm(float x) {
  return __builtin_amdgcn_rcpf(1.0f + __expf(-x));
}
__device__ __forceinline__ float tanh_fast(float x) {
  float ax = fabsf(x);
  float e = __expf(2.0f * ax);
  float t = 1.0f - 2.0f * __builtin_amdgcn_rcpf(e + 1.0f);
  return copysignf(t, x);
}

__global__ void prep_weights(const float* __restrict__ Wix, const float* __restrict__ Wih,
                             const float* __restrict__ Wfx, const float* __restrict__ Wfh,
                             const float* __restrict__ Wox, const float* __restrict__ Woh,
                             const float* __restrict__ Wux, const float* __restrict__ Wuh,
                             u16* __restrict__ Wcat, u16* __restrict__ Wfxb, u16* __restrict__ Wfhb)
{
  int t = blockIdx.x * 256 + threadIdx.x;
  if (t < 98304) {                 // Wcat: 384 rows x 256 k
    int nrow = t >> 8, k = t & 255;
    int gate = nrow >> 7, r = nrow & 127;
    float v;
    if (k < 128) {
      const float* W = (gate == 0) ? Wix : (gate == 1) ? Wox : Wux;
      v = W[r * 128 + k];
    } else {
      const float* W = (gate == 0) ? Wih : (gate == 1) ? Woh : Wuh;
      v = W[r * 128 + (k - 128)];
    }
    Wcat[t] = f2bf(v);
  } else if (t < 98304 + 16384) {
    int i = t - 98304;
    Wfxb[i] = f2bf(Wfx[i]);
  } else if (t < 98304 + 32768) {
    int i = t - 98304 - 16384;
    Wfhb[i] = f2bf(Wfh[i]);
  }
}

// MODE: 0 = leaf, 1 = internal (levels 6..3; all tiles full).
// 64 nodes/block, 512 threads (8 waves); wave w owns within-gate cols
// [16w,16w+16). Produces fc (f32) + hsum (bf16) for the parent level.
template <int MODE>
__global__ __launch_bounds__(512, 2)
void tree_kernel(const float* __restrict__ embeds,
                 const u16* __restrict__ Wcat,
                 const u16* __restrict__ Wfxb,
                 const u16* __restrict__ Wfhb,
                 const float* __restrict__ bix, const float* __restrict__ bfx,
                 const float* __restrict__ box, const float* __restrict__ bux,
                 u16* __restrict__ hf, float* __restrict__ fc_buf,
                 int noff, int poff)
{
  constexpr bool HASC = (MODE >= 1);   // consumes fc + hsum
  constexpr int OFF_SHS  = 16384;
  constexpr int OFF_SFXP = OFF_SHS + (HASC ? 16384 : 0);
  constexpr int SMEM_SZ  = OFF_SFXP + 16 * 132 * 4;
  __shared__ char smem[SMEM_SZ];
  u16*   sx   = (u16*)smem;                    // 64 x 256B swz bf16 (x, later h)
  u16*   shs  = (u16*)(smem + OFF_SHS);        // 64 x 256B swz bf16 (hsum)
  float* sfxp = (float*)(smem + OFF_SFXP);     // [16][132] f32 (fx_parent)

  const int tid  = threadIdx.x;
  const int wave = tid >> 6;
  const int lane = tid & 63;
  const int lg   = lane >> 4;
  const int ln   = lane & 15;
  const int pbase = blockIdx.x * 64;
  const int col  = wave * 16 + ln;
  const int prow0 = poff + (pbase >> 2);       // first parent row

  // ---- stage x (64 rows) ----
  {
    int row = tid >> 3;
    int k0  = (tid & 7) * 16;
    const float* src = embeds + (size_t)(noff + pbase + row) * HID + k0;
    unsigned sw = ((unsigned)(row & 7)) << 4;
    char* dst = (char*)sx + row * 256;
    float4 f0 = *(const float4*)src;
    float4 f1 = *(const float4*)(src + 4);
    float4 f2 = *(const float4*)(src + 8);
    float4 f3 = *(const float4*)(src + 12);
    *(short8*)(dst + (((unsigned)(k0 * 2)) ^ sw))      = f2bf8(f0, f1);
    *(short8*)(dst + (((unsigned)(k0 * 2 + 16)) ^ sw)) = f2bf8(f2, f3);
  }
  // ---- stage hsum (64 rows, from hf) ----
  if constexpr (HASC) {
    int row = tid >> 3, cg = tid & 7;
    const u16* src = hf + (size_t)(noff + pbase + row) * HID + cg * 16;
    short8 v0 = *(const short8*)src;
    short8 v1 = *(const short8*)(src + 8);
    unsigned sw = ((unsigned)(row & 7)) << 4;
    char* dst = (char*)shs + row * 256;
    *(short8*)(dst + ((cg * 32) ^ sw))      = v0;
    *(short8*)(dst + ((cg * 32 + 16) ^ sw)) = v1;
  }
  __syncthreads();

  // ---- batch-load own fc (produced by child level) ----
  float fcown[4][4];
  if constexpr (HASC) {
#pragma unroll
    for (int m = 0; m < 4; ++m)
#pragma unroll
      for (int r = 0; r < 4; ++r)
        fcown[m][r] = fc_buf[(size_t)(noff + pbase + m * 16 + lg * 4 + r) * HID + col];
  }

  // ---- main GEMM: [x | hsum] @ Wcat^T ----
  floatx4 acc[4][3] = {};
  constexpr int KT = HASC ? 8 : 4;
#pragma unroll
  for (int kt = 0; kt < KT; ++kt) {
    short8 a[4];
#pragma unroll
    for (int m = 0; m < 4; ++m) {
      int row = m * 16 + ln;
      unsigned sw = ((unsigned)(row & 7)) << 4;
      const char* base = (kt < 4) ? (const char*)sx : (const char*)shs;
      int kb = ((kt & 3) * 32 + lg * 8) * 2;
      a[m] = *(const short8*)(base + row * 256 + (((unsigned)kb) ^ sw));
    }
#pragma unroll
    for (int g = 0; g < 3; ++g) {
      short8 b = *(const short8*)(Wcat + (size_t)((g * 8 + wave) * 16 + ln) * 256 + kt * 32 + lg * 8);
#pragma unroll
      for (int m = 0; m < 4; ++m)
        acc[m][g] = __builtin_amdgcn_mfma_f32_16x16x32_bf16(a[m], b, acc[m][g], 0, 0, 0);
    }
  }

  // ---- fx_parent GEMM (16 rows, K=128); parent-x frags direct from global ----
  {
    floatx4 accxp = {};
    const float* xprow = embeds + (size_t)(prow0 + ln) * HID;
#pragma unroll
    for (int kt = 0; kt < 4; ++kt) {
      short8 b = *(const short8*)(Wfxb + (size_t)(wave * 16 + ln) * HID + kt * 32 + lg * 8);
      float4 f0 = *(const float4*)(xprow + kt * 32 + lg * 8);
      float4 f1 = *(const float4*)(xprow + kt * 32 + lg * 8 + 4);
      accxp = __builtin_amdgcn_mfma_f32_16x16x32_bf16(f2bf8(f0, f1), b, accxp, 0, 0, 0);
    }
#pragma unroll
    for (int r = 0; r < 4; ++r)
      sfxp[(lg * 4 + r) * 132 + col] = accxp[r];
  }
  __syncthreads();   // sx reads done (h will overwrite); sfxp visible

  // ---- epilogue: gates; c kept in f32 regs; h -> sx; hsum -> hf ----
  float cv[4][4];
  {
    float bi = bix[col], bo = box[col], bu = bux[col];
#pragma unroll
    for (int m = 0; m < 4; ++m) {
      float hs4 = 0.f;
#pragma unroll
      for (int r = 0; r < 4; ++r) {
        int row = m * 16 + lg * 4 + r;
        float iv = sigm(acc[m][0][r] + bi);
        float ov = sigm(acc[m][1][r] + bo);
        float uv = tanh_fast(acc[m][2][r] + bu);
        float fcv = HASC ? fcown[m][r] : 0.f;
        float c = iv * uv + fcv;
        float hv = ov * tanh_fast(c);
        cv[m][r] = c;
        hs4 += hv;
        unsigned sw = ((unsigned)(row & 7)) << 4;
        *(u16*)((char*)sx + row * 256 + (((unsigned)(col * 2)) ^ sw)) = f2bf(hv);
      }
      hf[(size_t)(prow0 + m * 4 + lg) * HID + col] = f2bf(hs4);
    }
  }

  // ---- fh GEMM on LDS h tile; in-lane fc for parents; write fc (f32) ----
  {
    __syncthreads();   // h writes to sx visible
    floatx4 ah[4] = {};
#pragma unroll
    for (int kt = 0; kt < 4; ++kt) {
      short8 b = *(const short8*)(Wfhb + (size_t)(wave * 16 + ln) * HID + kt * 32 + lg * 8);
#pragma unroll
      for (int m = 0; m < 4; ++m) {
        int row = m * 16 + ln;
        unsigned sw = ((unsigned)(row & 7)) << 4;
        short8 a = *(const short8*)((char*)sx + row * 256 +
                                    (((unsigned)((kt * 32 + lg * 8) * 2)) ^ sw));
        ah[m] = __builtin_amdgcn_mfma_f32_16x16x32_bf16(a, b, ah[m], 0, 0, 0);
      }
    }
    float bf = bfx[col];
#pragma unroll
    for (int m = 0; m < 4; ++m) {
      float fxv = sfxp[(m * 4 + lg) * 132 + col] + bf;
      float s = 0.f;
#pragma unroll
      for (int r = 0; r < 4; ++r)
        s += sigm(fxv + ah[m][r]) * cv[m][r];
      fc_buf[(size_t)(prow0 + m * 4 + lg) * HID + col] = s;
    }
  }
}

// ---------------- Fused tail: levels 2..0 + output head; 4 blocks x 4 trees ----------------
// Block b owns trees 4b..4b+3. Per level the block consumes fc/hsum it wrote
// itself in the previous iteration (same-block global RAW via __syncthreads).
// Padded rows (l<2) read finite garbage that is masked from all valid outputs.
__global__ __launch_bounds__(512, 2)
void fused_tail(const float* __restrict__ embeds,
                const u16* __restrict__ Wcat,
                const u16* __restrict__ Wfxb,
                const u16* __restrict__ Wfhb,
                const float* __restrict__ bix, const float* __restrict__ bfx,
                const float* __restrict__ box, const float* __restrict__ bux,
                const float* __restrict__ Wout, const float* __restrict__ bout,
                u16* __restrict__ hf, float* __restrict__ fc_buf,
                float* __restrict__ out)
{
  __shared__ char smem[16384 + 16384 + 16 * 132 * 4];
  u16*   sx   = (u16*)smem;
  u16*   shs  = (u16*)(smem + 16384);
  float* sfxp = (float*)(smem + 32768);

  const int tid  = threadIdx.x;
  const int wave = tid >> 6;
  const int lane = tid & 63;
  const int lg   = lane >> 4;
  const int ln   = lane & 15;
  const int col  = wave * 16 + ln;
  const int b    = blockIdx.x;

  const int offs[3] = {0, 16, 80};

#pragma unroll 1
  for (int l = 2; l >= 0; --l) {
    const int nrows = 64 >> (2 * (2 - l));          // 64, 16, 4
    const int noff  = offs[l] + b * nrows;
    const bool last = (l == 0);
    const int poff  = last ? 0 : offs[l - 1] + b * (nrows >> 2);

    // ---- stage x (64 rows; rows >= nrows garbage, masked) ----
    {
      int row = tid >> 3;
      int k0  = (tid & 7) * 16;
      const float* src = embeds + (size_t)(noff + row) * HID + k0;
      unsigned sw = ((unsigned)(row & 7)) << 4;
      char* dst = (char*)sx + row * 256;
      float4 f0 = *(const float4*)src;
      float4 f1 = *(const float4*)(src + 4);
      float4 f2 = *(const float4*)(src + 8);
      float4 f3 = *(const float4*)(src + 12);
      *(short8*)(dst + (((unsigned)(k0 * 2)) ^ sw))      = f2bf8(f0, f1);
      *(short8*)(dst + (((unsigned)(k0 * 2 + 16)) ^ sw)) = f2bf8(f2, f3);
    }
    // ---- stage hsum ----
    {
      int row = tid >> 3, cg = tid & 7;
      const u16* src = hf + (size_t)(noff + row) * HID + cg * 16;
      short8 v0 = *(const short8*)src;
      short8 v1 = *(const short8*)(src + 8);
      unsigned sw = ((unsigned)(row & 7)) << 4;
      char* dst = (char*)shs + row * 256;
      *(short8*)(dst + ((cg * 32) ^ sw))      = v0;
      *(short8*)(dst + ((cg * 32 + 16) ^ sw)) = v1;
    }
    __syncthreads();

    // ---- own fc ----
    float fcown[4][4];
#pragma unroll
    for (int m = 0; m < 4; ++m)
#pragma unroll
      for (int r = 0; r < 4; ++r)
        fcown[m][r] = fc_buf[(size_t)(noff + m * 16 + lg * 4 + r) * HID + col];

    // ---- main GEMM K=256 ----
    floatx4 acc[4][3] = {};
#pragma unroll
    for (int kt = 0; kt < 8; ++kt) {
      short8 a[4];
#pragma unroll
      for (int m = 0; m < 4; ++m) {
        int row = m * 16 + ln;
        unsigned sw = ((unsigned)(row & 7)) << 4;
        const char* base = (kt < 4) ? (const char*)sx : (const char*)shs;
        int kb = ((kt & 3) * 32 + lg * 8) * 2;
        a[m] = *(const short8*)(base + row * 256 + (((unsigned)kb) ^ sw));
      }
#pragma unroll
      for (int g = 0; g < 3; ++g) {
        short8 bb = *(const short8*)(Wcat + (size_t)((g * 8 + wave) * 16 + ln) * 256 + kt * 32 + lg * 8);
#pragma unroll
        for (int m = 0; m < 4; ++m)
          acc[m][g] = __builtin_amdgcn_mfma_f32_16x16x32_bf16(a[m], bb, acc[m][g], 0, 0, 0);
      }
    }

    // ---- fx_parent GEMM (direct global A-frags) ----
    if (!last) {
      floatx4 accxp = {};
      const float* xprow = embeds + (size_t)(poff + ln) * HID;
#pragma unroll
      for (int kt = 0; kt < 4; ++kt) {
        short8 bb = *(const short8*)(Wfxb + (size_t)(wave * 16 + ln) * HID + kt * 32 + lg * 8);
        float4 f0 = *(const float4*)(xprow + kt * 32 + lg * 8);
        float4 f1 = *(const float4*)(xprow + kt * 32 + lg * 8 + 4);
        accxp = __builtin_amdgcn_mfma_f32_16x16x32_bf16(f2bf8(f0, f1), bb, accxp, 0, 0, 0);
      }
#pragma unroll
      for (int r = 0; r < 4; ++r)
        sfxp[(lg * 4 + r) * 132 + col] = accxp[r];
    }
    __syncthreads();

    // ---- epilogue (rows < nrows) ----
    float cv[4][4];
    {
      float bi = bix[col], bo = box[col], bu = bux[col];
#pragma unroll
      for (int m = 0; m < 4; ++m) {
        float hs4 = 0.f;
#pragma unroll
        for (int r = 0; r < 4; ++r) {
          int row = m * 16 + lg * 4 + r;
          if (row < nrows) {
            float iv = sigm(acc[m][0][r] + bi);
            float ov = sigm(acc[m][1][r] + bo);
            float uv = tanh_fast(acc[m][2][r] + bu);
            float c = iv * uv + fcown[m][r];
            float hv = ov * tanh_fast(c);
            cv[m][r] = c;
            hs4 += hv;
            unsigned sw = ((unsigned)(row & 7)) << 4;
            *(u16*)((char*)sx + row * 256 + (((unsigned)(col * 2)) ^ sw)) = f2bf(hv);
          }
        }
        if (!last && (m * 4 + lg) < (nrows >> 2))
          hf[(size_t)(poff + m * 4 + lg) * HID + col] = f2bf(hs4);
      }
    }

    if (!last) {
      __syncthreads();   // h writes visible
      floatx4 ah[4] = {};
#pragma unroll
      for (int kt = 0; kt < 4; ++kt) {
        short8 bb = *(const short8*)(Wfhb + (size_t)(wave * 16 + ln) * HID + kt * 32 + lg * 8);
#pragma unroll
        for (int m = 0; m < 4; ++m) {
          int row = m * 16 + ln;
          unsigned sw = ((unsigned)(row & 7)) << 4;
          short8 a = *(const short8*)((char*)sx + row * 256 +
                                      (((unsigned)((kt * 32 + lg * 8) * 2)) ^ sw));
          ah[m] = __builtin_amdgcn_mfma_f32_16x16x32_bf16(a, bb, ah[m], 0, 0, 0);
        }
      }
      float bf = bfx[col];
#pragma unroll
      for (int m = 0; m < 4; ++m) {
        if ((m * 4 + lg) < (nrows >> 2)) {
          float fxv = sfxp[(m * 4 + lg) * 132 + col] + bf;
          float s = 0.f;
#pragma unroll
          for (int r = 0; r < 4; ++r)
            s += sigm(fxv + ah[m][r]) * cv[m][r];
          fc_buf[(size_t)(poff + m * 4 + lg) * HID + col] = s;
        }
      }
    }
    __syncthreads();   // protect sx/shs reuse (and expose root h in sx)
  }

  // ---- output head: roots of trees 4b..4b+3 are sx rows 0..3 ----
  if (tid < 20) {
    int r = tid / 5, lbl = tid - r * 5;
    unsigned sw = ((unsigned)r) << 4;
    float s = bout[lbl];
    const float* wr = Wout + lbl * 128;
    const char* hrow = (const char*)sx + r * 256;
#pragma unroll 4
    for (int k = 0; k < 128; ++k)
      s += bf2f(*(const u16*)(hrow + (((unsigned)(k * 2)) ^ sw))) * wr[k];
    out[(4 * b + r) * 5 + lbl] = s;
  }
}

extern "C" void kernel_launch(void* const* d_in, const int* in_sizes, int n_in,
                              void* d_out, int out_size, void* d_ws, size_t ws_size,
                              hipStream_t stream)
{
  const float* embeds = (const float*)d_in[0];
  const float* Wix = (const float*)d_in[1];
  const float* bix = (const float*)d_in[2];
  const float* Wih = (const float*)d_in[3];
  const float* Wfx = (const float*)d_in[4];
  const float* bfx = (const float*)d_in[5];
  const float* Wfh = (const float*)d_in[6];
  const float* Wox = (const float*)d_in[7];
  const float* box = (const float*)d_in[8];
  const float* Woh = (const float*)d_in[9];
  const float* Wux = (const float*)d_in[10];
  const float* bux = (const float*)d_in[11];
  const float* Wuh = (const float*)d_in[12];
  const float* Wout = (const float*)d_in[13];
  const float* bout = (const float*)d_in[14];

  static const int counts[8]  = {16, 64, 256, 1024, 4096, 16384, 65536, 262144};
  static const int offsets[9] = {0, 16, 80, 336, 1360, 5456, 21840, 87376, 349520};

  char* ws = (char*)d_ws;
  u16*   hf     = (u16*)ws;                                  // 89,477,120 B
  float* fc_buf = (float*)(ws + 89477120);                   // 178,954,240 B
  u16*   Wcat   = (u16*)(ws + 89477120 + 178954240);         // 196,608 B
  u16*   Wfxb   = Wcat + 384 * 256;
  u16*   Wfhb   = Wfxb + 128 * 128;

  prep_weights<<<512, 256, 0, stream>>>(Wix, Wih, Wfx, Wfh, Wox, Woh, Wux, Wuh,
                                        Wcat, Wfxb, Wfhb);

  // level 7 (leaves): produces fc + hsum for level 6
  tree_kernel<0><<<262144 / 64, 512, 0, stream>>>(
      embeds, Wcat, Wfxb, Wfhb, bix, bfx, box, bux,
      hf, fc_buf, 87376, 21840);

  // levels 6..3
  for (int l = 6; l >= 3; --l) {
    int nl = counts[l];
    tree_kernel<1><<<nl / 64, 512, 0, stream>>>(
        embeds, Wcat, Wfxb, Wfhb, bix, bfx, box, bux,
        hf, fc_buf, offsets[l], offsets[l - 1]);
  }

  // levels 2..0 + output head, fused (4 blocks x 4 trees)
  fused_tail<<<4, 512, 0, stream>>>(
      embeds, Wcat, Wfxb, Wfhb, bix, bfx, box, bux,
      Wout, bout, hf, fc_buf, (float*)d_out);
}

// Round 20
// 245.551 us; speedup vs baseline: 1.1163x; 1.1163x over previous
//
#include <hip/hip_runtime.h>
#include <hip/hip_bf16.h>

// Child-Sum Tree-LSTM, 16 trees x branch4 x depth8, HIDDEN=IN_DIM=128.
// R20 = R16's tree_kernel verbatim (sxp LDS staging restored -- R19's
//       direct-global parent-x regressed the leaf 141->164us) for levels 7..3,
//       + R19's fused_tail (levels 2..0 + output head, 4 blocks x 4 trees).

#define HID 128

typedef unsigned short u16;
typedef unsigned int u32;
typedef __attribute__((ext_vector_type(8))) short short8;
typedef __attribute__((ext_vector_type(4))) float floatx4;

__device__ __forceinline__ float bf2f(u16 u) {
  union { unsigned int u; float f; } v; v.u = ((unsigned int)u) << 16; return v.f;
}
__device__ __forceinline__ u16 f2bf(float f) {
  __hip_bfloat16 b = __float2bfloat16(f);           // native RNE cvt on gfx950
  return *reinterpret_cast<u16*>(&b);
}
__device__ __forceinline__ short8 f2bf8(float4 f0, float4 f1) {
  short8 s;
  s[0] = (short)f2bf(f0.x); s[1] = (short)f2bf(f0.y);
  s[2] = (short)f2bf(f0.z); s[3] = (short)f2bf(f0.w);
  s[4] = (short)f2bf(f1.x); s[5] = (short)f2bf(f1.y);
  s[6] = (short)f2bf(f1.z); s[7] = (short)f2bf(f1.w);
  return s;
}
__device__ __forceinline__ float sigm(float x) {
  return __builtin_amdgcn_rcpf(1.0f + __expf(-x));
}
__device__ __forceinline__ float tanh_fast(float x) {
  float ax = fabsf(x);
  float e = __expf(2.0f * ax);
  float t = 1.0f - 2.0f * __builtin_amdgcn_rcpf(e + 1.0f);
  return copysignf(t, x);
}

__global__ void prep_weights(const float* __restrict__ Wix, const float* __restrict__ Wih,
                             const float* __restrict__ Wfx, const float* __restrict__ Wfh,
                             const float* __restrict__ Wox, const float* __restrict__ Woh,
                             const float* __restrict__ Wux, const float* __restrict__ Wuh,
                             u16* __restrict__ Wcat, u16* __restrict__ Wfxb, u16* __restrict__ Wfhb)
{
  int t = blockIdx.x * 256 + threadIdx.x;
  if (t < 98304) {                 // Wcat: 384 rows x 256 k
    int nrow = t >> 8, k = t & 255;
    int gate = nrow >> 7, r = nrow & 127;
    float v;
    if (k < 128) {
      const float* W = (gate == 0) ? Wix : (gate == 1) ? Wox : Wux;
      v = W[r * 128 + k];
    } else {
      const float* W = (gate == 0) ? Wih : (gate == 1) ? Woh : Wuh;
      v = W[r * 128 + (k - 128)];
    }
    Wcat[t] = f2bf(v);
  } else if (t < 98304 + 16384) {
    int i = t - 98304;
    Wfxb[i] = f2bf(Wfx[i]);
  } else if (t < 98304 + 32768) {
    int i = t - 98304 - 16384;
    Wfhb[i] = f2bf(Wfh[i]);
  }
}

// MODE: 0 = leaf, 1 = internal (levels 6..3; all tiles full).
// 64 nodes/block, 512 threads (8 waves); wave w owns within-gate cols
// [16w,16w+16). Producers stage their 16 PARENT x rows in LDS (sxp),
// compute fx_parent, and write fc (f32) + hsum (bf16) for the parent level.
template <int MODE>
__global__ __launch_bounds__(512, 2)
void tree_kernel(const float* __restrict__ embeds,
                 const u16* __restrict__ Wcat,
                 const u16* __restrict__ Wfxb,
                 const u16* __restrict__ Wfhb,
                 const float* __restrict__ bix, const float* __restrict__ bfx,
                 const float* __restrict__ box, const float* __restrict__ bux,
                 u16* __restrict__ hf, float* __restrict__ fc_buf,
                 int noff, int poff)
{
  constexpr bool HASC = (MODE >= 1);   // consumes fc + hsum
  constexpr int OFF_SHS  = 16384;
  constexpr int OFF_SXP  = OFF_SHS + (HASC ? 16384 : 0);
  constexpr int OFF_SFXP = OFF_SXP + 4096;
  constexpr int SMEM_SZ  = OFF_SFXP + 16 * 132 * 4;
  __shared__ char smem[SMEM_SZ];
  u16*   sx   = (u16*)smem;                    // 64 x 256B swz bf16 (x, later h)
  u16*   shs  = (u16*)(smem + OFF_SHS);        // 64 x 256B swz bf16 (hsum)
  u16*   sxp  = (u16*)(smem + OFF_SXP);        // 16 x 256B swz bf16 (parent x)
  float* sfxp = (float*)(smem + OFF_SFXP);     // [16][132] f32 (fx_parent)

  const int tid  = threadIdx.x;
  const int wave = tid >> 6;
  const int lane = tid & 63;
  const int lg   = lane >> 4;
  const int ln   = lane & 15;
  const int pbase = blockIdx.x * 64;
  const int col  = wave * 16 + ln;
  const int prow0 = poff + (pbase >> 2);       // first parent row

  // ---- stage x (64 rows) ----
  {
    int row = tid >> 3;
    int k0  = (tid & 7) * 16;
    const float* src = embeds + (size_t)(noff + pbase + row) * HID + k0;
    unsigned sw = ((unsigned)(row & 7)) << 4;
    char* dst = (char*)sx + row * 256;
    float4 f0 = *(const float4*)src;
    float4 f1 = *(const float4*)(src + 4);
    float4 f2 = *(const float4*)(src + 8);
    float4 f3 = *(const float4*)(src + 12);
    *(short8*)(dst + (((unsigned)(k0 * 2)) ^ sw))      = f2bf8(f0, f1);
    *(short8*)(dst + (((unsigned)(k0 * 2 + 16)) ^ sw)) = f2bf8(f2, f3);
  }
  // ---- stage hsum (64 rows, from hf) ----
  if constexpr (HASC) {
    int row = tid >> 3, cg = tid & 7;
    const u16* src = hf + (size_t)(noff + pbase + row) * HID + cg * 16;
    short8 v0 = *(const short8*)src;
    short8 v1 = *(const short8*)(src + 8);
    unsigned sw = ((unsigned)(row & 7)) << 4;
    char* dst = (char*)shs + row * 256;
    *(short8*)(dst + ((cg * 32) ^ sw))      = v0;
    *(short8*)(dst + ((cg * 32 + 16) ^ sw)) = v1;
  }
  // ---- stage parent x (16 rows) ----
  {
    if (tid < 128) {
      int row = tid >> 3;
      int k0  = (tid & 7) * 16;
      const float* src = embeds + (size_t)(prow0 + row) * HID + k0;
      unsigned sw = ((unsigned)(row & 7)) << 4;
      char* dst = (char*)sxp + row * 256;
      float4 f0 = *(const float4*)src;
      float4 f1 = *(const float4*)(src + 4);
      float4 f2 = *(const float4*)(src + 8);
      float4 f3 = *(const float4*)(src + 12);
      *(short8*)(dst + (((unsigned)(k0 * 2)) ^ sw))      = f2bf8(f0, f1);
      *(short8*)(dst + (((unsigned)(k0 * 2 + 16)) ^ sw)) = f2bf8(f2, f3);
    }
  }
  __syncthreads();

  // ---- batch-load own fc (produced by child level) ----
  float fcown[4][4];
  if constexpr (HASC) {
#pragma unroll
    for (int m = 0; m < 4; ++m)
#pragma unroll
      for (int r = 0; r < 4; ++r)
        fcown[m][r] = fc_buf[(size_t)(noff + pbase + m * 16 + lg * 4 + r) * HID + col];
  }

  // ---- main GEMM: [x | hsum] @ Wcat^T ----
  floatx4 acc[4][3] = {};
  constexpr int KT = HASC ? 8 : 4;
#pragma unroll
  for (int kt = 0; kt < KT; ++kt) {
    short8 a[4];
#pragma unroll
    for (int m = 0; m < 4; ++m) {
      int row = m * 16 + ln;
      unsigned sw = ((unsigned)(row & 7)) << 4;
      const char* base = (kt < 4) ? (const char*)sx : (const char*)shs;
      int kb = ((kt & 3) * 32 + lg * 8) * 2;
      a[m] = *(const short8*)(base + row * 256 + (((unsigned)kb) ^ sw));
    }
#pragma unroll
    for (int g = 0; g < 3; ++g) {
      short8 b = *(const short8*)(Wcat + (size_t)((g * 8 + wave) * 16 + ln) * 256 + kt * 32 + lg * 8);
#pragma unroll
      for (int m = 0; m < 4; ++m)
        acc[m][g] = __builtin_amdgcn_mfma_f32_16x16x32_bf16(a[m], b, acc[m][g], 0, 0, 0);
    }
  }

  // ---- fx_parent GEMM (16 rows, K=128) -> sfxp ----
  {
    floatx4 accxp = {};
#pragma unroll
    for (int kt = 0; kt < 4; ++kt) {
      short8 b = *(const short8*)(Wfxb + (size_t)(wave * 16 + ln) * HID + kt * 32 + lg * 8);
      unsigned sw = ((unsigned)(ln & 7)) << 4;
      short8 a = *(const short8*)((char*)sxp + ln * 256 +
                                  (((unsigned)((kt * 32 + lg * 8) * 2)) ^ sw));
      accxp = __builtin_amdgcn_mfma_f32_16x16x32_bf16(a, b, accxp, 0, 0, 0);
    }
#pragma unroll
    for (int r = 0; r < 4; ++r)
      sfxp[(lg * 4 + r) * 132 + col] = accxp[r];
  }
  __syncthreads();   // sx reads done (h will overwrite); sfxp visible

  // ---- epilogue: gates; c kept in f32 regs; h -> sx; hsum -> hf ----
  float cv[4][4];
  {
    float bi = bix[col], bo = box[col], bu = bux[col];
#pragma unroll
    for (int m = 0; m < 4; ++m) {
      float hs4 = 0.f;
#pragma unroll
      for (int r = 0; r < 4; ++r) {
        int row = m * 16 + lg * 4 + r;
        float iv = sigm(acc[m][0][r] + bi);
        float ov = sigm(acc[m][1][r] + bo);
        float uv = tanh_fast(acc[m][2][r] + bu);
        float fcv = HASC ? fcown[m][r] : 0.f;
        float c = iv * uv + fcv;
        float hv = ov * tanh_fast(c);
        cv[m][r] = c;
        hs4 += hv;
        unsigned sw = ((unsigned)(row & 7)) << 4;
        *(u16*)((char*)sx + row * 256 + (((unsigned)(col * 2)) ^ sw)) = f2bf(hv);
      }
      hf[(size_t)(prow0 + m * 4 + lg) * HID + col] = f2bf(hs4);
    }
  }

  // ---- fh GEMM on LDS h tile; in-lane fc for parents; write fc (f32) ----
  {
    __syncthreads();   // h writes to sx visible
    floatx4 ah[4] = {};
#pragma unroll
    for (int kt = 0; kt < 4; ++kt) {
      short8 b = *(const short8*)(Wfhb + (size_t)(wave * 16 + ln) * HID + kt * 32 + lg * 8);
#pragma unroll
      for (int m = 0; m < 4; ++m) {
        int row = m * 16 + ln;
        unsigned sw = ((unsigned)(row & 7)) << 4;
        short8 a = *(const short8*)((char*)sx + row * 256 +
                                    (((unsigned)((kt * 32 + lg * 8) * 2)) ^ sw));
        ah[m] = __builtin_amdgcn_mfma_f32_16x16x32_bf16(a, b, ah[m], 0, 0, 0);
      }
    }
    float bf = bfx[col];
#pragma unroll
    for (int m = 0; m < 4; ++m) {
      float fxv = sfxp[(m * 4 + lg) * 132 + col] + bf;
      float s = 0.f;
#pragma unroll
      for (int r = 0; r < 4; ++r)
        s += sigm(fxv + ah[m][r]) * cv[m][r];
      fc_buf[(size_t)(prow0 + m * 4 + lg) * HID + col] = s;
    }
  }
}

// ---------------- Fused tail: levels 2..0 + output head; 4 blocks x 4 trees ----------------
// Block b owns trees 4b..4b+3. Per level the block consumes fc/hsum it wrote
// itself in the previous iteration (same-block global RAW via __syncthreads).
// Padded rows (l<2) read finite garbage that is masked from all valid outputs.
__global__ __launch_bounds__(512, 2)
void fused_tail(const float* __restrict__ embeds,
                const u16* __restrict__ Wcat,
                const u16* __restrict__ Wfxb,
                const u16* __restrict__ Wfhb,
                const float* __restrict__ bix, const float* __restrict__ bfx,
                const float* __restrict__ box, const float* __restrict__ bux,
                const float* __restrict__ Wout, const float* __restrict__ bout,
                u16* __restrict__ hf, float* __restrict__ fc_buf,
                float* __restrict__ out)
{
  __shared__ char smem[16384 + 16384 + 16 * 132 * 4];
  u16*   sx   = (u16*)smem;
  u16*   shs  = (u16*)(smem + 16384);
  float* sfxp = (float*)(smem + 32768);

  const int tid  = threadIdx.x;
  const int wave = tid >> 6;
  const int lane = tid & 63;
  const int lg   = lane >> 4;
  const int ln   = lane & 15;
  const int col  = wave * 16 + ln;
  const int b    = blockIdx.x;

  const int offs[3] = {0, 16, 80};

#pragma unroll 1
  for (int l = 2; l >= 0; --l) {
    const int nrows = 64 >> (2 * (2 - l));          // 64, 16, 4
    const int noff  = offs[l] + b * nrows;
    const bool last = (l == 0);
    const int poff  = last ? 0 : offs[l - 1] + b * (nrows >> 2);

    // ---- stage x (64 rows; rows >= nrows garbage, masked) ----
    {
      int row = tid >> 3;
      int k0  = (tid & 7) * 16;
      const float* src = embeds + (size_t)(noff + row) * HID + k0;
      unsigned sw = ((unsigned)(row & 7)) << 4;
      char* dst = (char*)sx + row * 256;
      float4 f0 = *(const float4*)src;
      float4 f1 = *(const float4*)(src + 4);
      float4 f2 = *(const float4*)(src + 8);
      float4 f3 = *(const float4*)(src + 12);
      *(short8*)(dst + (((unsigned)(k0 * 2)) ^ sw))      = f2bf8(f0, f1);
      *(short8*)(dst + (((unsigned)(k0 * 2 + 16)) ^ sw)) = f2bf8(f2, f3);
    }
    // ---- stage hsum ----
    {
      int row = tid >> 3, cg = tid & 7;
      const u16* src = hf + (size_t)(noff + row) * HID + cg * 16;
      short8 v0 = *(const short8*)src;
      short8 v1 = *(const short8*)(src + 8);
      unsigned sw = ((unsigned)(row & 7)) << 4;
      char* dst = (char*)shs + row * 256;
      *(short8*)(dst + ((cg * 32) ^ sw))      = v0;
      *(short8*)(dst + ((cg * 32 + 16) ^ sw)) = v1;
    }
    __syncthreads();

    // ---- own fc ----
    float fcown[4][4];
#pragma unroll
    for (int m = 0; m < 4; ++m)
#pragma unroll
      for (int r = 0; r < 4; ++r)
        fcown[m][r] = fc_buf[(size_t)(noff + m * 16 + lg * 4 + r) * HID + col];

    // ---- main GEMM K=256 ----
    floatx4 acc[4][3] = {};
#pragma unroll
    for (int kt = 0; kt < 8; ++kt) {
      short8 a[4];
#pragma unroll
      for (int m = 0; m < 4; ++m) {
        int row = m * 16 + ln;
        unsigned sw = ((unsigned)(row & 7)) << 4;
        const char* base = (kt < 4) ? (const char*)sx : (const char*)shs;
        int kb = ((kt & 3) * 32 + lg * 8) * 2;
        a[m] = *(const short8*)(base + row * 256 + (((unsigned)kb) ^ sw));
      }
#pragma unroll
      for (int g = 0; g < 3; ++g) {
        short8 bb = *(const short8*)(Wcat + (size_t)((g * 8 + wave) * 16 + ln) * 256 + kt * 32 + lg * 8);
#pragma unroll
        for (int m = 0; m < 4; ++m)
          acc[m][g] = __builtin_amdgcn_mfma_f32_16x16x32_bf16(a[m], bb, acc[m][g], 0, 0, 0);
      }
    }

    // ---- fx_parent GEMM (direct global A-frags; tiny, 3 iterations total) ----
    if (!last) {
      floatx4 accxp = {};
      const float* xprow = embeds + (size_t)(poff + ln) * HID;
#pragma unroll
      for (int kt = 0; kt < 4; ++kt) {
        short8 bb = *(const short8*)(Wfxb + (size_t)(wave * 16 + ln) * HID + kt * 32 + lg * 8);
        float4 f0 = *(const float4*)(xprow + kt * 32 + lg * 8);
        float4 f1 = *(const float4*)(xprow + kt * 32 + lg * 8 + 4);
        accxp = __builtin_amdgcn_mfma_f32_16x16x32_bf16(f2bf8(f0, f1), bb, accxp, 0, 0, 0);
      }
#pragma unroll
      for (int r = 0; r < 4; ++r)
        sfxp[(lg * 4 + r) * 132 + col] = accxp[r];
    }
    __syncthreads();

    // ---- epilogue (rows < nrows) ----
    float cv[4][4];
    {
      float bi = bix[col], bo = box[col], bu = bux[col];
#pragma unroll
      for (int m = 0; m < 4; ++m) {
        float hs4 = 0.f;
#pragma unroll
        for (int r = 0; r < 4; ++r) {
          int row = m * 16 + lg * 4 + r;
          if (row < nrows) {
            float iv = sigm(acc[m][0][r] + bi);
            float ov = sigm(acc[m][1][r] + bo);
            float uv = tanh_fast(acc[m][2][r] + bu);
            float c = iv * uv + fcown[m][r];
            float hv = ov * tanh_fast(c);
            cv[m][r] = c;
            hs4 += hv;
            unsigned sw = ((unsigned)(row & 7)) << 4;
            *(u16*)((char*)sx + row * 256 + (((unsigned)(col * 2)) ^ sw)) = f2bf(hv);
          }
        }
        if (!last && (m * 4 + lg) < (nrows >> 2))
          hf[(size_t)(poff + m * 4 + lg) * HID + col] = f2bf(hs4);
      }
    }

    if (!last) {
      __syncthreads();   // h writes visible
      floatx4 ah[4] = {};
#pragma unroll
      for (int kt = 0; kt < 4; ++kt) {
        short8 bb = *(const short8*)(Wfhb + (size_t)(wave * 16 + ln) * HID + kt * 32 + lg * 8);
#pragma unroll
        for (int m = 0; m < 4; ++m) {
          int row = m * 16 + ln;
          unsigned sw = ((unsigned)(row & 7)) << 4;
          short8 a = *(const short8*)((char*)sx + row * 256 +
                                      (((unsigned)((kt * 32 + lg * 8) * 2)) ^ sw));
          ah[m] = __builtin_amdgcn_mfma_f32_16x16x32_bf16(a, bb, ah[m], 0, 0, 0);
        }
      }
      float bf = bfx[col];
#pragma unroll
      for (int m = 0; m < 4; ++m) {
        if ((m * 4 + lg) < (nrows >> 2)) {
          float fxv = sfxp[(m * 4 + lg) * 132 + col] + bf;
          float s = 0.f;
#pragma unroll
          for (int r = 0; r < 4; ++r)
            s += sigm(fxv + ah[m][r]) * cv[m][r];
          fc_buf[(size_t)(poff + m * 4 + lg) * HID + col] = s;
        }
      }
    }
    __syncthreads();   // protect sx/shs reuse (and expose root h in sx)
  }

  // ---- output head: roots of trees 4b..4b+3 are sx rows 0..3 ----
  if (tid < 20) {
    int r = tid / 5, lbl = tid - r * 5;
    unsigned sw = ((unsigned)r) << 4;
    float s = bout[lbl];
    const float* wr = Wout + lbl * 128;
    const char* hrow = (const char*)sx + r * 256;
#pragma unroll 4
    for (int k = 0; k < 128; ++k)
      s += bf2f(*(const u16*)(hrow + (((unsigned)(k * 2)) ^ sw))) * wr[k];
    out[(4 * b + r) * 5 + lbl] = s;
  }
}

extern "C" void kernel_launch(void* const* d_in, const int* in_sizes, int n_in,
                              void* d_out, int out_size, void* d_ws, size_t ws_size,
                              hipStream_t stream)
{
  const float* embeds = (const float*)d_in[0];
  const float* Wix = (const float*)d_in[1];
  const float* bix = (const float*)d_in[2];
  const float* Wih = (const float*)d_in[3];
  const float* Wfx = (const float*)d_in[4];
  const float* bfx = (const float*)d_in[5];
  const float* Wfh = (const float*)d_in[6];
  const float* Wox = (const float*)d_in[7];
  const float* box = (const float*)d_in[8];
  const float* Woh = (const float*)d_in[9];
  const float* Wux = (const float*)d_in[10];
  const float* bux = (const float*)d_in[11];
  const float* Wuh = (const float*)d_in[12];
  const float* Wout = (const float*)d_in[13];
  const float* bout = (const float*)d_in[14];

  static const int counts[8]  = {16, 64, 256, 1024, 4096, 16384, 65536, 262144};
  static const int offsets[9] = {0, 16, 80, 336, 1360, 5456, 21840, 87376, 349520};

  char* ws = (char*)d_ws;
  u16*   hf     = (u16*)ws;                                  // 89,477,120 B
  float* fc_buf = (float*)(ws + 89477120);                   // 178,954,240 B
  u16*   Wcat   = (u16*)(ws + 89477120 + 178954240);         // 196,608 B
  u16*   Wfxb   = Wcat + 384 * 256;
  u16*   Wfhb   = Wfxb + 128 * 128;

  prep_weights<<<512, 256, 0, stream>>>(Wix, Wih, Wfx, Wfh, Wox, Woh, Wux, Wuh,
                                        Wcat, Wfxb, Wfhb);

  // level 7 (leaves): produces fc + hsum for level 6
  tree_kernel<0><<<262144 / 64, 512, 0, stream>>>(
      embeds, Wcat, Wfxb, Wfhb, bix, bfx, box, bux,
      hf, fc_buf, 87376, 21840);

  // levels 6..3
  for (int l = 6; l >= 3; --l) {
    int nl = counts[l];
    tree_kernel<1><<<nl / 64, 512, 0, stream>>>(
        embeds, Wcat, Wfxb, Wfhb, bix, bfx, box, bux,
        hf, fc_buf, offsets[l], offsets[l - 1]);
  }

  // levels 2..0 + output head, fused (4 blocks x 4 trees)
  fused_tail<<<4, 512, 0, stream>>>(
      embeds, Wcat, Wfxb, Wfhb, bix, bfx, box, bux,
      Wout, bout, hf, fc_buf, (float*)d_out);
}